// Round 3
// baseline (78.175 us; speedup 1.0000x reference)
//
#include <hip/hip_runtime.h>
#include <math.h>

#define BSZ 4096
#define NTOK 8192
#define NVEC (BSZ * NTOK / 4)   // 2^23 float4s

#define NBLOCKS 2048
#define NTHREADS 256
#define STRIDE (NBLOCKS * NTHREADS)  // 524288; NVEC = 16*STRIDE exactly
#define UNROLL 4                      // 4 outer iters x 4 = 16

__global__ __launch_bounds__(NTHREADS) void gauss_nll_partial(
    const float4* __restrict__ mu,
    const float4* __restrict__ sigma,
    const float4* __restrict__ ty,
    float* __restrict__ partials) {
    int tid = blockIdx.x * NTHREADS + threadIdx.x;

    float acc0 = 0.0f, acc1 = 0.0f, acc2 = 0.0f, acc3 = 0.0f;

    for (int k = 0; k < 4; ++k) {
        int base = tid + k * (UNROLL * STRIDE);
        float4 m[UNROLL], s[UNROLL], t[UNROLL];
        // Batch ALL loads first — 12 x 16B in flight per wave.
#pragma unroll
        for (int j = 0; j < UNROLL; ++j) m[j] = mu[base + j * STRIDE];
#pragma unroll
        for (int j = 0; j < UNROLL; ++j) s[j] = sigma[base + j * STRIDE];
#pragma unroll
        for (int j = 0; j < UNROLL; ++j) t[j] = ty[base + j * STRIDE];

        float d0, d1, d2, d3;
#pragma unroll
        for (int j = 0; j < UNROLL; ++j) {
            d0 = t[j].x - m[j].x;
            d1 = t[j].y - m[j].y;
            d2 = t[j].z - m[j].z;
            d3 = t[j].w - m[j].w;
            float r0 = __logf(s[j].x) + d0 * d0 * __builtin_amdgcn_rcpf(s[j].x);
            float r1 = __logf(s[j].y) + d1 * d1 * __builtin_amdgcn_rcpf(s[j].y);
            float r2 = __logf(s[j].z) + d2 * d2 * __builtin_amdgcn_rcpf(s[j].z);
            float r3 = __logf(s[j].w) + d3 * d3 * __builtin_amdgcn_rcpf(s[j].w);
            if (j == 0) acc0 += r0 + r1 + r2 + r3;
            else if (j == 1) acc1 += r0 + r1 + r2 + r3;
            else if (j == 2) acc2 += r0 + r1 + r2 + r3;
            else acc3 += r0 + r1 + r2 + r3;
        }
    }
    float acc = (acc0 + acc1) + (acc2 + acc3);

    // wave-64 butterfly reduce
    for (int off = 32; off > 0; off >>= 1)
        acc += __shfl_down(acc, off, 64);

    __shared__ float wsum[NTHREADS / 64];
    int lane = threadIdx.x & 63;
    int wid = threadIdx.x >> 6;
    if (lane == 0) wsum[wid] = acc;
    __syncthreads();
    if (threadIdx.x == 0) {
        partials[blockIdx.x] = wsum[0] + wsum[1] + wsum[2] + wsum[3];
    }
}

__global__ __launch_bounds__(256) void gauss_nll_final(
    const float* __restrict__ partials, float* __restrict__ out) {
    float acc = 0.0f;
    for (int i = threadIdx.x; i < NBLOCKS; i += 256)
        acc += partials[i];
    for (int off = 32; off > 0; off >>= 1)
        acc += __shfl_down(acc, off, 64);
    __shared__ float wsum[4];
    int lane = threadIdx.x & 63;
    int wid = threadIdx.x >> 6;
    if (lane == 0) wsum[wid] = acc;
    __syncthreads();
    if (threadIdx.x == 0) {
        float total = wsum[0] + wsum[1] + wsum[2] + wsum[3];
        const float log2pi = 1.8378770664093453f;  // log(2*pi)
        out[0] = 0.5f * ((float)NTOK * log2pi + total / (float)BSZ);
    }
}

extern "C" void kernel_launch(void* const* d_in, const int* in_sizes, int n_in,
                              void* d_out, int out_size, void* d_ws, size_t ws_size,
                              hipStream_t stream) {
    const float4* mu = (const float4*)d_in[0];
    const float4* sigma = (const float4*)d_in[1];
    const float4* ty = (const float4*)d_in[2];
    float* out = (float*)d_out;
    float* partials = (float*)d_ws;  // NBLOCKS floats, fully written each call

    gauss_nll_partial<<<NBLOCKS, NTHREADS, 0, stream>>>(mu, sigma, ty, partials);
    gauss_nll_final<<<1, 256, 0, stream>>>(partials, out);
}

// Round 4
// 72.699 us; speedup vs baseline: 1.0753x; 1.0753x over previous
//
#include <hip/hip_runtime.h>
#include <math.h>

#define BSZ 4096
#define NTOK 8192
#define NVEC (BSZ * NTOK / 4)   // 2^23 float4s

#define NBLOCKS 8192            // 32 blocks/CU worth — fine-grain for rebalance
#define NTHREADS 256
#define PER_BLOCK (NVEC / NBLOCKS)   // 1024 float4s per stream per block
#define UNROLL 4                     // 4 float4-triples per thread

__global__ __launch_bounds__(NTHREADS) void gauss_nll_partial(
    const float4* __restrict__ mu,
    const float4* __restrict__ sigma,
    const float4* __restrict__ ty,
    float* __restrict__ partials) {
    // Block b owns the contiguous range [b*1024, (b+1)*1024) of each stream.
    int base = blockIdx.x * PER_BLOCK + threadIdx.x;

    float4 m[UNROLL], s[UNROLL], t[UNROLL];
#pragma unroll
    for (int j = 0; j < UNROLL; ++j) m[j] = mu[base + j * NTHREADS];
#pragma unroll
    for (int j = 0; j < UNROLL; ++j) s[j] = sigma[base + j * NTHREADS];
#pragma unroll
    for (int j = 0; j < UNROLL; ++j) t[j] = ty[base + j * NTHREADS];

    float acc = 0.0f;
#pragma unroll
    for (int j = 0; j < UNROLL; ++j) {
        float d0 = t[j].x - m[j].x;
        float d1 = t[j].y - m[j].y;
        float d2 = t[j].z - m[j].z;
        float d3 = t[j].w - m[j].w;
        float r0 = __logf(s[j].x) + d0 * d0 * __builtin_amdgcn_rcpf(s[j].x);
        float r1 = __logf(s[j].y) + d1 * d1 * __builtin_amdgcn_rcpf(s[j].y);
        float r2 = __logf(s[j].z) + d2 * d2 * __builtin_amdgcn_rcpf(s[j].z);
        float r3 = __logf(s[j].w) + d3 * d3 * __builtin_amdgcn_rcpf(s[j].w);
        acc += (r0 + r1) + (r2 + r3);
    }

    // wave-64 butterfly reduce
    for (int off = 32; off > 0; off >>= 1)
        acc += __shfl_down(acc, off, 64);

    __shared__ float wsum[NTHREADS / 64];
    int lane = threadIdx.x & 63;
    int wid = threadIdx.x >> 6;
    if (lane == 0) wsum[wid] = acc;
    __syncthreads();
    if (threadIdx.x == 0) {
        partials[blockIdx.x] = wsum[0] + wsum[1] + wsum[2] + wsum[3];
    }
}

__global__ __launch_bounds__(1024) void gauss_nll_final(
    const float* __restrict__ partials, float* __restrict__ out) {
    float acc = 0.0f;
    for (int i = threadIdx.x; i < NBLOCKS; i += 1024)
        acc += partials[i];
    for (int off = 32; off > 0; off >>= 1)
        acc += __shfl_down(acc, off, 64);
    __shared__ float wsum[16];
    int lane = threadIdx.x & 63;
    int wid = threadIdx.x >> 6;
    if (lane == 0) wsum[wid] = acc;
    __syncthreads();
    if (threadIdx.x == 0) {
        float total = 0.0f;
        for (int i = 0; i < 16; ++i) total += wsum[i];
        const float log2pi = 1.8378770664093453f;  // log(2*pi)
        out[0] = 0.5f * ((float)NTOK * log2pi + total / (float)BSZ);
    }
}

extern "C" void kernel_launch(void* const* d_in, const int* in_sizes, int n_in,
                              void* d_out, int out_size, void* d_ws, size_t ws_size,
                              hipStream_t stream) {
    const float4* mu = (const float4*)d_in[0];
    const float4* sigma = (const float4*)d_in[1];
    const float4* ty = (const float4*)d_in[2];
    float* out = (float*)d_out;
    float* partials = (float*)d_ws;  // NBLOCKS floats, fully written each call

    gauss_nll_partial<<<NBLOCKS, NTHREADS, 0, stream>>>(mu, sigma, ty, partials);
    gauss_nll_final<<<1, 1024, 0, stream>>>(partials, out);
}